// Round 9
// baseline (56.360 us; speedup 1.0000x reference)
//
#include <hip/hip_runtime.h>
#include <float.h>

#define N_NODES_C 200000
#define HIDDEN_C 256
#define NSEG_C 1024
#define NEG_SLOPE_C 0.2f
#define NWAVE_C 8
#define NBLK_C 1024
#define SLOT_F 260   // {m, d, pad, pad, acc[256]}

typedef float f32x4 __attribute__((ext_vector_type(4)));

__device__ __forceinline__ int block_of_row(int r) {
    // block b covers rows [ (b*N)>>10, ((b+1)*N)>>10 )
    return (int)((((size_t)(r + 1) << 10) - 1) / N_NODES_C);
}

// ---------- Kernel 1: perfectly balanced rows; per-piece online softmax ----------
__global__ __launch_bounds__(512, 8)
void attn_part_bal(const float* __restrict__ feature,
                   const float* __restrict__ a,
                   const int* __restrict__ batch,
                   float* __restrict__ slots,   // [NBLK][2][SLOT_F]
                   float* __restrict__ out) {
    const int b    = blockIdx.x;
    const int tid  = threadIdx.x;
    const int lane = tid & 63;
    const int wid  = tid >> 6;

    const int r0  = (int)(((size_t)b * N_NODES_C) >> 10);
    const int r1  = (int)(((size_t)(b + 1) * N_NODES_C) >> 10);
    const int len = r1 - r0;            // 195 or 196

    __shared__ float part[NWAVE_C][HIDDEN_C];
    __shared__ float md[NWAVE_C][2];
    __shared__ int   bl[208];           // batch[r0 .. r1)
    __shared__ unsigned long long bmask[4];
    __shared__ int   pstart[208];
    __shared__ int   pcount;
    __shared__ int   sentL, sentR;

    if (tid < len) bl[tid] = batch[r0 + tid];
    if (tid == 0) sentL = (r0 > 0) ? batch[r0 - 1] : -1;
    if (tid == 1) sentR = (r1 < N_NODES_C) ? batch[r1] : -1;
    __syncthreads();

    // piece-start flags (tid==0 always a start) -> per-wave ballot masks
    const bool flag = (tid < len) && (tid == 0 || bl[tid] != bl[tid - 1]);
    const unsigned long long wm = __ballot(flag);
    if (lane == 0 && wid < 4) bmask[wid] = wm;
    __syncthreads();

    if (tid == 0)
        pcount = __popcll(bmask[0]) + __popcll(bmask[1])
               + __popcll(bmask[2]) + __popcll(bmask[3]);
    if (tid < 200) {                    // thread k extracts k-th set bit
        int k = tid, pos = -1;
        #pragma unroll
        for (int w = 0; w < 4; ++w) {
            const int c = __popcll(bmask[w]);
            if (pos < 0) {
                if (k < c) {
                    unsigned long long mm = bmask[w];
                    for (int t = 0; t < k; ++t) mm &= mm - 1;
                    pos = w * 64 + (int)__builtin_ctzll(mm);
                } else k -= c;
            }
        }
        if (pos >= 0) pstart[tid] = pos;
    }
    __syncthreads();
    const int P = pcount;

    const float4 av = *reinterpret_cast<const float4*>(a + 4 * lane);

    auto ldrow = [&](int i) -> f32x4 {
        return __builtin_nontemporal_load(
            reinterpret_cast<const f32x4*>(feature + (size_t)i * HIDDEN_C + 4 * lane));
    };
    auto dotred = [&](const f32x4& f) -> float {
        float p = f.x * av.x + f.y * av.y + f.z * av.z + f.w * av.w;
        #pragma unroll
        for (int off = 32; off >= 1; off >>= 1)
            p += __shfl_xor(p, off, 64);
        return (p > 0.0f) ? p : NEG_SLOPE_C * p;
    };

    for (int pk = 0; pk < P; ++pk) {
        const int lst  = pstart[pk];
        const int lend = (pk + 1 < P) ? pstart[pk + 1] : len;
        const int p0 = r0 + lst, p1 = r0 + lend;
        const int s  = bl[lst];

        float m = -FLT_MAX;
        float d = 0.0f;
        f32x4 acc = {0.f, 0.f, 0.f, 0.f};

        auto online = [&](float l, const f32x4& f) {
            if (l > m) {
                const float sc = __expf(m - l);
                acc.x = acc.x * sc + f.x;
                acc.y = acc.y * sc + f.y;
                acc.z = acc.z * sc + f.z;
                acc.w = acc.w * sc + f.w;
                d = d * sc + 1.0f;
                m = l;
            } else {
                const float w = __expf(l - m);
                acc.x += w * f.x;
                acc.y += w * f.y;
                acc.z += w * f.z;
                acc.w += w * f.w;
                d += w;
            }
        };

        int i = p0 + wid;
        if (i + NWAVE_C < p1) {
            f32x4 f0 = ldrow(i);
            f32x4 f1 = ldrow(i + NWAVE_C);
            i += 2 * NWAVE_C;
            for (; i + NWAVE_C < p1; i += 2 * NWAVE_C) {
                const f32x4 n0 = ldrow(i);
                const f32x4 n1 = ldrow(i + NWAVE_C);
                const float l0 = dotred(f0);
                const float l1 = dotred(f1);
                online(l0, f0);
                online(l1, f1);
                f0 = n0; f1 = n1;
            }
            const float l0 = dotred(f0);
            const float l1 = dotred(f1);
            online(l0, f0);
            online(l1, f1);
        }
        for (; i < p1; i += NWAVE_C) {
            const f32x4 f = ldrow(i);
            online(dotred(f), f);
        }

        part[wid][4 * lane + 0] = acc.x;
        part[wid][4 * lane + 1] = acc.y;
        part[wid][4 * lane + 2] = acc.z;
        part[wid][4 * lane + 3] = acc.w;
        if (lane == 0) { md[wid][0] = m; md[wid][1] = d; }
        __syncthreads();

        float M = md[0][0];
        #pragma unroll
        for (int k = 1; k < NWAVE_C; ++k) M = fmaxf(M, md[k][0]);
        float D = 0.0f, v = 0.0f;
        if (tid < HIDDEN_C) {
            #pragma unroll
            for (int k = 0; k < NWAVE_C; ++k) {
                const float e = __expf(md[k][0] - M);   // empty wave: exp(-inf)=0
                D += e * md[k][1];
                v += e * part[k][tid];
            }
        }

        const bool extL = (lst == 0) && (sentL == s);
        const bool extR = (lend == len) && (sentR == s);
        if (!extL && !extR) {
            // complete segment inside this block -> final output
            if (tid < HIDDEN_C)
                out[(size_t)s * HIDDEN_C + tid] = v / (D * (float)(p1 - p0));
        } else {
            if (extL) {
                float* sl = slots + ((size_t)b * 2 + 0) * SLOT_F;
                if (tid < HIDDEN_C) sl[4 + tid] = v;
                if (tid == 0) { sl[0] = M; sl[1] = D; }
            }
            if (extR) {
                float* sl = slots + ((size_t)b * 2 + 1) * SLOT_F;
                if (tid < HIDDEN_C) sl[4 + tid] = v;
                if (tid == 0) { sl[0] = M; sl[1] = D; }
            }
        }
        __syncthreads();   // part/md reused by next piece
    }
}

// ---------- Kernel 2: merge cross-block segments ----------
__global__ __launch_bounds__(256, 8)
void attn_merge_bal(const int* __restrict__ batch,
                    const float* __restrict__ slots,
                    float* __restrict__ out) {
    const int s    = blockIdx.x;
    const int tid  = threadIdx.x;
    const int lane = tid & 63;
    const int wid  = tid >> 6;

    __shared__ int sb[2];

    if (wid < 2) {                      // R8's verified 3-phase probe search
        const int target = s + wid;
        int lo = 0;
        int step = 3125;
        #pragma unroll
        for (int ph = 0; ph < 3; ++ph) {
            const int idx = lo + lane * step;
            const int v = (idx < N_NODES_C) ? batch[idx] : 0x7fffffff;
            const unsigned long long mask = __ballot(v < target);
            if (mask) lo += (63 - __builtin_clzll(mask)) * step + 1;
            step = (step == 3125) ? 49 : 1;
        }
        if (lane == 0) sb[wid] = lo;
    }
    __syncthreads();
    const int s0 = sb[0], s1 = sb[1], cnt = s1 - s0;

    if (cnt == 0) {
        out[(size_t)s * HIDDEN_C + tid] = 0.0f;
        return;
    }

    const int b0 = block_of_row(s0);
    const int b1 = block_of_row(s1 - 1);
    if (b0 == b1) return;               // kernel 1 wrote the final value

    float M = -FLT_MAX;
    for (int bb = b0; bb <= b1; ++bb) {
        const int side = (bb == b0) ? 1 : 0;
        M = fmaxf(M, slots[((size_t)bb * 2 + side) * SLOT_F]);
    }
    float D = 0.0f, v = 0.0f;
    for (int bb = b0; bb <= b1; ++bb) {
        const int side = (bb == b0) ? 1 : 0;
        const float* sl = slots + ((size_t)bb * 2 + side) * SLOT_F;
        const float e = __expf(sl[0] - M);
        D += e * sl[1];
        v += e * sl[4 + tid];
    }
    out[(size_t)s * HIDDEN_C + tid] = v / (D * (float)cnt);
}

// ---------- Fallback: R8 single-kernel (proven 39.6 us) ----------
__global__ __launch_bounds__(512, 8)
void attn_pool(const float* __restrict__ feature,
               const float* __restrict__ a,
               const int* __restrict__ batch,
               float* __restrict__ out) {
    const int s    = blockIdx.x;
    const int tid  = threadIdx.x;
    const int lane = tid & 63;
    const int wid  = tid >> 6;

    __shared__ float part[NWAVE_C][HIDDEN_C];
    __shared__ float md[NWAVE_C][2];
    __shared__ int   sb[2];

    if (wid < 2) {
        const int target = s + wid;
        int lo = 0;
        int step = 3125;
        #pragma unroll
        for (int ph = 0; ph < 3; ++ph) {
            const int idx = lo + lane * step;
            const int v = (idx < N_NODES_C) ? batch[idx] : 0x7fffffff;
            const unsigned long long mask = __ballot(v < target);
            if (mask) lo += (63 - __builtin_clzll(mask)) * step + 1;
            step = (step == 3125) ? 49 : 1;
        }
        if (lane == 0) sb[wid] = lo;
    }
    __syncthreads();
    const int s0 = sb[0], s1 = sb[1], cnt = s1 - s0;

    if (cnt == 0) {
        if (tid < HIDDEN_C) out[(size_t)s * HIDDEN_C + tid] = 0.0f;
        return;
    }

    const float4 av = *reinterpret_cast<const float4*>(a + 4 * lane);

    float m = -FLT_MAX;
    float d = 0.0f;
    f32x4 acc = {0.f, 0.f, 0.f, 0.f};

    auto ldrow = [&](int i) -> f32x4 {
        return __builtin_nontemporal_load(
            reinterpret_cast<const f32x4*>(feature + (size_t)i * HIDDEN_C + 4 * lane));
    };
    auto dotred = [&](const f32x4& f) -> float {
        float p = f.x * av.x + f.y * av.y + f.z * av.z + f.w * av.w;
        #pragma unroll
        for (int off = 32; off >= 1; off >>= 1)
            p += __shfl_xor(p, off, 64);
        return (p > 0.0f) ? p : NEG_SLOPE_C * p;
    };
    auto online = [&](float l, const f32x4& f) {
        if (l > m) {
            const float sc = __expf(m - l);
            acc.x = acc.x * sc + f.x;
            acc.y = acc.y * sc + f.y;
            acc.z = acc.z * sc + f.z;
            acc.w = acc.w * sc + f.w;
            d = d * sc + 1.0f;
            m = l;
        } else {
            const float w = __expf(l - m);
            acc.x += w * f.x;
            acc.y += w * f.y;
            acc.z += w * f.z;
            acc.w += w * f.w;
            d += w;
        }
    };

    int i = s0 + wid;
    if (i + NWAVE_C < s1) {
        f32x4 f0 = ldrow(i);
        f32x4 f1 = ldrow(i + NWAVE_C);
        i += 2 * NWAVE_C;
        for (; i + NWAVE_C < s1; i += 2 * NWAVE_C) {
            const f32x4 n0 = ldrow(i);
            const f32x4 n1 = ldrow(i + NWAVE_C);
            const float l0 = dotred(f0);
            const float l1 = dotred(f1);
            online(l0, f0);
            online(l1, f1);
            f0 = n0; f1 = n1;
        }
        const float l0 = dotred(f0);
        const float l1 = dotred(f1);
        online(l0, f0);
        online(l1, f1);
    }
    if (i < s1) {
        const f32x4 f = ldrow(i);
        online(dotred(f), f);
    }

    part[wid][4 * lane + 0] = acc.x;
    part[wid][4 * lane + 1] = acc.y;
    part[wid][4 * lane + 2] = acc.z;
    part[wid][4 * lane + 3] = acc.w;
    if (lane == 0) { md[wid][0] = m; md[wid][1] = d; }
    __syncthreads();

    if (tid < HIDDEN_C) {
        float M = md[0][0];
        #pragma unroll
        for (int k = 1; k < NWAVE_C; ++k) M = fmaxf(M, md[k][0]);
        float D = 0.0f, v = 0.0f;
        #pragma unroll
        for (int k = 0; k < NWAVE_C; ++k) {
            const float e = __expf(md[k][0] - M);
            D += e * md[k][1];
            v += e * part[k][tid];
        }
        out[(size_t)s * HIDDEN_C + tid] = v / (D * (float)cnt);
    }
}

extern "C" void kernel_launch(void* const* d_in, const int* in_sizes, int n_in,
                              void* d_out, int out_size, void* d_ws, size_t ws_size,
                              hipStream_t stream) {
    const float* feature = (const float*)d_in[0];
    const float* a       = (const float*)d_in[1];
    const int*   batch   = (const int*)d_in[2];
    float* out = (float*)d_out;
    (void)in_sizes; (void)n_in; (void)out_size;

    const size_t slotBytes = (size_t)NBLK_C * 2 * SLOT_F * sizeof(float);  // ~2.13 MB

    if (ws_size >= slotBytes) {
        float* slots = (float*)d_ws;
        attn_part_bal<<<NBLK_C, 512, 0, stream>>>(feature, a, batch, slots, out);
        attn_merge_bal<<<NSEG_C, 256, 0, stream>>>(batch, slots, out);
    } else {
        attn_pool<<<NSEG_C, 512, 0, stream>>>(feature, a, batch, out);
    }
}